// Round 6
// baseline (1890.698 us; speedup 1.0000x reference)
//
#include <hip/hip_runtime.h>
#include <math.h>

// SGC: out = log_softmax((A_hat^2 x) W + b), A_hat = D^-1/2 (A+I) D^-1/2
// (A^2 X) W == A^2 (X W): propagate in 40-dim class space.
// Z = D^-1/2 Y: Z' = di^2 (sum_s Z_s + Z_i) -> pure gather-add.
// Gathered Z buffers bf16 (80 B rows = 2 lines/edge, 8 MB footprint).
// Round-6: gemm tile 128 nodes (782 blocks; round-5's 391 blocks left CUs
// starved at 16% occupancy) and hop-2 fused with bias+log_softmax (kills a
// 32 MB round-trip + a launch).

#define FDIM 128
#define CDIM 40
#define C4   10
#define BKT_SHIFT 8
#define NB   512   // bucket slots (>= ceil(N/256))
#define NBLK 512   // edge-partition blocks
#define NPB  51    // nodes per 256-thread prop block (5 lanes/node)

// ---------- bf16 helpers (RTNE pack; finite inputs) ----------
__device__ __forceinline__ unsigned int bf16rn(float f) {
    unsigned int u = __float_as_uint(f);
    return (u + 0x7fffu + ((u >> 16) & 1u)) >> 16;
}
__device__ __forceinline__ unsigned int pack2(float lo, float hi) {
    unsigned int a = bf16rn(lo);
    unsigned int b = __float_as_uint(hi);
    b = (b + 0x7fffu + ((b >> 16) & 1u)) & 0xffff0000u;
    return a | b;
}
__device__ __forceinline__ void addu4(uint4 u, float* a) {
    a[0] += __uint_as_float(u.x << 16);
    a[1] += __uint_as_float(u.x & 0xffff0000u);
    a[2] += __uint_as_float(u.y << 16);
    a[3] += __uint_as_float(u.y & 0xffff0000u);
    a[4] += __uint_as_float(u.z << 16);
    a[5] += __uint_as_float(u.z & 0xffff0000u);
    a[6] += __uint_as_float(u.w << 16);
    a[7] += __uint_as_float(u.w & 0xffff0000u);
}

// ---- pass 1: per-block histogram over dst buckets (LDS, no global atomics)
__global__ void hist_k(const int* __restrict__ dst, int* __restrict__ G,
                       int E, int EB) {
    __shared__ int h[NB];
    int t = threadIdx.x;
    for (int i = t; i < NB; i += 256) h[i] = 0;
    __syncthreads();
    int s = blockIdx.x * EB;
    int e = min(s + EB, E);
    for (int i = s + t; i < e; i += 256)
        atomicAdd(&h[dst[i] >> BKT_SHIFT], 1);
    __syncthreads();
    for (int i = t; i < NB; i += 256) G[blockIdx.x * NB + i] = h[i];
}

// ---- pass 2: per-bucket exclusive scan over blocks (in-place on G); totals->T
__global__ void colscan_k(int* __restrict__ G, int* __restrict__ T) {
    __shared__ int lds[256];
    int j = blockIdx.x;
    int t = threadIdx.x;
    int v0 = G[(2 * t) * NB + j];
    int v1 = G[(2 * t + 1) * NB + j];
    int s = v0 + v1;
    lds[t] = s;
    __syncthreads();
    for (int off = 1; off < 256; off <<= 1) {
        int a = (t >= off) ? lds[t - off] : 0;
        __syncthreads();
        lds[t] += a;
        __syncthreads();
    }
    int excl = lds[t] - s;
    G[(2 * t) * NB + j] = excl;
    G[(2 * t + 1) * NB + j] = excl + v0;
    if (t == 255) T[j] = lds[255];
}

// ---- pass 2b: exclusive scan of bucket totals -> bs[0..NB], bs[NB]=E
__global__ void bscan_k(const int* __restrict__ T, int* __restrict__ bs) {
    __shared__ int lds[256];
    int t = threadIdx.x;
    int v0 = T[2 * t];
    int v1 = T[2 * t + 1];
    int s = v0 + v1;
    lds[t] = s;
    __syncthreads();
    for (int off = 1; off < 256; off <<= 1) {
        int a = (t >= off) ? lds[t - off] : 0;
        __syncthreads();
        lds[t] += a;
        __syncthreads();
    }
    int excl = lds[t] - s;
    bs[2 * t] = excl;
    bs[2 * t + 1] = excl + v0;
    if (t == 255) bs[NB] = lds[255];
}

// ---- pass 3: scatter packed edges into bucket-partitioned tmp
// pack: src (24 bits) | dstLocal (8 bits) << 24   [requires N < 2^24]
__global__ void part_k(const int* __restrict__ src, const int* __restrict__ dst,
                       const int* __restrict__ G, const int* __restrict__ bs,
                       unsigned int* __restrict__ tmp, int E, int EB) {
    __shared__ int offs[NB];
    __shared__ int cur[NB];
    int t = threadIdx.x;
    for (int i = t; i < NB; i += 256) {
        offs[i] = bs[i] + G[blockIdx.x * NB + i];
        cur[i] = 0;
    }
    __syncthreads();
    int s = blockIdx.x * EB;
    int e = min(s + EB, E);
    for (int i = s + t; i < e; i += 256) {
        int d = dst[i];
        int j = d >> BKT_SHIFT;
        int r = atomicAdd(&cur[j], 1);
        tmp[offs[j] + r] = (unsigned int)src[i] | ((unsigned int)(d & 255) << 24);
    }
}

// ---- pass 4: one block per bucket: rowptr/dinv/dsq + CSR col fill (all local)
__global__ void csr_k(const unsigned int* __restrict__ tmp, const int* __restrict__ bs,
                      int* __restrict__ rowptr, float* __restrict__ dinv,
                      float* __restrict__ dsq, int* __restrict__ col, int N, int E) {
    __shared__ int cnt[256];
    __shared__ int ptr[256];
    int j = blockIdx.x;
    int t = threadIdx.x;
    int base = j << BKT_SHIFT;
    int s = bs[j];
    int e = bs[j + 1];
    cnt[t] = 0;
    __syncthreads();
    for (int i = s + t; i < e; i += 256)
        atomicAdd(&cnt[tmp[i] >> 24], 1);
    __syncthreads();
    int v = cnt[t];
    ptr[t] = v;
    __syncthreads();
    for (int off = 1; off < 256; off <<= 1) {
        int a = (t >= off) ? ptr[t - off] : 0;
        __syncthreads();
        ptr[t] += a;
        __syncthreads();
    }
    int excl = ptr[t] - v;
    int node = base + t;
    if (node < N) {
        rowptr[node] = s + excl;
        float d = (float)(v + 1);              // +1 self-loop
        dinv[node] = rsqrtf(d);
        dsq[node] = sqrtf(d);
    }
    if (j == 0 && t == 0) rowptr[N] = E;
    cnt[t] = excl;  // cursor
    __syncthreads();
    for (int i = s + t; i < e; i += 256) {
        unsigned int p = tmp[i];
        int loc = p >> 24;
        int r = atomicAdd(&cnt[loc], 1);
        col[s + r] = (int)(p & 0xFFFFFF);
    }
}

// ---- Z0[node][40] (bf16) = dinv[node] * (x[node] @ W)
// 128-node tile, 320 threads; thread = 2 nodes x 8 classes.
// xT[32][129]: stage conflict-checked (<=2-way everywhere = free).
// W rows wave-uniform (cg = t>>6 constant per wave) -> LDS broadcast.
__global__ __launch_bounds__(320) void gemm_k(const float* __restrict__ x,
                                              const float* __restrict__ W,
                                              const float* __restrict__ dinv,
                                              uint4* __restrict__ Zbf, int n) {
    __shared__ float Ws[FDIM * CDIM];   // 20 KB
    __shared__ float xT[32][129];       // 16.5 KB
    int t = threadIdx.x;
    for (int i = t; i < FDIM * CDIM; i += 320) Ws[i] = W[i];
    int base = blockIdx.x * 128;
    int cg = t >> 6;   // 0..4 (8 classes each) -> one uint4 per node
    int ng = t & 63;   // nodes {ng, ng+64}
    float acc[2][8];
    #pragma unroll
    for (int k = 0; k < 2; ++k)
        #pragma unroll
        for (int c = 0; c < 8; ++c) acc[k][c] = 0.f;

    for (int ch = 0; ch < 4; ++ch) {
        __syncthreads();
        for (int i = t; i < 1024; i += 320) {
            int f4 = i & 7;
            int nn = i >> 3;
            int node = base + nn;
            float4 xv = make_float4(0.f, 0.f, 0.f, 0.f);
            if (node < n)
                xv = *(const float4*)(x + (size_t)node * FDIM + ch * 32 + f4 * 4);
            xT[f4 * 4 + 0][nn] = xv.x;
            xT[f4 * 4 + 1][nn] = xv.y;
            xT[f4 * 4 + 2][nn] = xv.z;
            xT[f4 * 4 + 3][nn] = xv.w;
        }
        __syncthreads();
        for (int f = 0; f < 32; ++f) {
            float x0 = xT[f][ng];
            float x1 = xT[f][ng + 64];
            const float* wr = &Ws[(ch * 32 + f) * CDIM + cg * 8];
            float4 w0 = *(const float4*)(wr);
            float4 w1 = *(const float4*)(wr + 4);
            float wv[8] = {w0.x, w0.y, w0.z, w0.w, w1.x, w1.y, w1.z, w1.w};
            #pragma unroll
            for (int c = 0; c < 8; ++c) {
                acc[0][c] += x0 * wv[c];
                acc[1][c] += x1 * wv[c];
            }
        }
    }
    #pragma unroll
    for (int k = 0; k < 2; ++k) {
        int node = base + ng + 64 * k;
        if (node >= n) continue;
        float di = dinv[node];
        uint4 o;
        o.x = pack2(acc[k][0] * di, acc[k][1] * di);
        o.y = pack2(acc[k][2] * di, acc[k][3] * di);
        o.z = pack2(acc[k][4] * di, acc[k][5] * di);
        o.w = pack2(acc[k][6] * di, acc[k][7] * di);
        Zbf[(size_t)node * 5 + cg] = o;
    }
}

// ---- one hop: acc = sum_{s->i} Zin[s] + Zin[i]; Zout = di^2 * acc.
// FINAL: fuse logits = Z2*dsq + b and log_softmax, write fp32 d_out.
// 5 lanes/node x uint4 (8 bf16); 51 nodes per 256-thread block.
template <bool FINAL>
__global__ __launch_bounds__(256) void prop_k(const int* __restrict__ rowptr,
                                              const int* __restrict__ col,
                                              const float* __restrict__ dinv,
                                              const float* __restrict__ dsq,
                                              const float* __restrict__ bias,
                                              const uint4* __restrict__ Zin,
                                              uint4* __restrict__ Zout_bf,
                                              float* __restrict__ out_f32, int n) {
    __shared__ float bsm[CDIM];
    __shared__ float red[256];
    int t = threadIdx.x;
    if (FINAL && t < CDIM) bsm[t] = bias[t];
    int g = t / 5;
    int c8 = t - g * 5;
    int node = blockIdx.x * NPB + g;
    bool active = (g < NPB) && (node < n);
    float acc[8];
    #pragma unroll
    for (int c = 0; c < 8; ++c) acc[c] = 0.f;
    float w = 0.f;
    if (active) {
        float di = dinv[node];
        w = di * di;
        addu4(Zin[(size_t)node * 5 + c8], acc);   // self-loop
        int e = rowptr[node];
        int end = rowptr[node + 1];
        for (; e + 3 < end; e += 4) {
            int s0 = col[e], s1 = col[e + 1], s2 = col[e + 2], s3 = col[e + 3];
            uint4 a0 = Zin[(size_t)s0 * 5 + c8];
            uint4 a1 = Zin[(size_t)s1 * 5 + c8];
            uint4 a2 = Zin[(size_t)s2 * 5 + c8];
            uint4 a3 = Zin[(size_t)s3 * 5 + c8];
            addu4(a0, acc); addu4(a1, acc); addu4(a2, acc); addu4(a3, acc);
        }
        for (; e < end; ++e)
            addu4(Zin[(size_t)col[e] * 5 + c8], acc);
    }

    if (!FINAL) {
        if (active) {
            uint4 o;
            o.x = pack2(acc[0] * w, acc[1] * w);
            o.y = pack2(acc[2] * w, acc[3] * w);
            o.z = pack2(acc[4] * w, acc[5] * w);
            o.w = pack2(acc[6] * w, acc[7] * w);
            Zout_bf[(size_t)node * 5 + c8] = o;
        }
        return;
    }

    // FINAL: logits + log_softmax via 5-lane LDS reduction.
    __syncthreads();  // bsm ready
    float v[8];
    float m8 = -INFINITY;
    if (active) {
        float ws_ = w * dsq[node];
        #pragma unroll
        for (int j = 0; j < 8; ++j) {
            v[j] = acc[j] * ws_ + bsm[c8 * 8 + j];
            m8 = fmaxf(m8, v[j]);
        }
    }
    red[t] = m8;
    __syncthreads();
    float m = m8;
    if (active) {
        int rb = g * 5;
        m = fmaxf(fmaxf(fmaxf(red[rb], red[rb + 1]), fmaxf(red[rb + 2], red[rb + 3])),
                  red[rb + 4]);
    }
    float s8 = 0.f;
    if (active) {
        #pragma unroll
        for (int j = 0; j < 8; ++j) s8 += expf(v[j] - m);
    }
    __syncthreads();
    red[t] = s8;
    __syncthreads();
    if (active) {
        int rb = g * 5;
        float s = (red[rb] + red[rb + 1]) + (red[rb + 2] + red[rb + 3]) + red[rb + 4];
        float ls = m + logf(s);
        float* p = out_f32 + (size_t)node * CDIM + c8 * 8;
        *(float4*)p = make_float4(v[0] - ls, v[1] - ls, v[2] - ls, v[3] - ls);
        *(float4*)(p + 4) = make_float4(v[4] - ls, v[5] - ls, v[6] - ls, v[7] - ls);
    }
}

extern "C" void kernel_launch(void* const* d_in, const int* in_sizes, int n_in,
                              void* d_out, int out_size, void* d_ws, size_t ws_size,
                              hipStream_t stream) {
    const float* x = (const float*)d_in[0];
    const float* W = (const float*)d_in[1];
    const float* b = (const float*)d_in[2];
    const int* ei = (const int*)d_in[3];

    int C = in_sizes[2];            // 40
    int F = in_sizes[1] / C;        // 128
    int N = in_sizes[0] / F;        // 100000
    int E = in_sizes[3] / 2;        // 1600000
    const int* src = ei;
    const int* dst = ei + E;

    // workspace: union region holds {G,T,bs,tmp} during build, then Z0bf (8MB).
    // Zb (hop-1 bf16 out, 8MB) lives separately: hop-2 gathers from it while
    // writing d_out, so it cannot alias d_out.
    char* ws = (char*)d_ws;
    size_t goff = 0;
    int* G = (int*)(ws + goff);                       goff += (size_t)NBLK * NB * 4;
    int* T = (int*)(ws + goff);                       goff += (size_t)NB * 4;
    int* bs = (int*)(ws + goff);                      goff += (size_t)(NB + 1) * 4 + 12;
    goff = (goff + 15) & ~(size_t)15;
    unsigned int* tmp = (unsigned int*)(ws + goff);   goff += (size_t)E * 4;
    size_t z0bytes = (size_t)N * 80;                  // 5 x uint4 per node
    size_t unionEnd = (z0bytes > goff) ? z0bytes : goff;
    unionEnd = (unionEnd + 15) & ~(size_t)15;
    uint4* Z0bf = (uint4*)ws;        // overlays build scratch
    size_t off = unionEnd;
    int* rowptr = (int*)(ws + off); off += ((size_t)(N + 1) * 4 + 15) & ~(size_t)15;
    float* dinv = (float*)(ws + off); off += ((size_t)N * 4 + 15) & ~(size_t)15;
    float* dsq = (float*)(ws + off); off += ((size_t)N * 4 + 15) & ~(size_t)15;
    int* col = (int*)(ws + off); off += ((size_t)E * 4 + 15) & ~(size_t)15;
    uint4* Zb = (uint4*)(ws + off); off += (z0bytes + 15) & ~(size_t)15;

    int EB = (E + NBLK - 1) / NBLK;
    int NBr = (N + 255) >> BKT_SHIFT;

    hist_k<<<NBLK, 256, 0, stream>>>(dst, G, E, EB);
    colscan_k<<<NB, 256, 0, stream>>>(G, T);
    bscan_k<<<1, 256, 0, stream>>>(T, bs);
    part_k<<<NBLK, 256, 0, stream>>>(src, dst, G, bs, tmp, E, EB);
    csr_k<<<NBr, 256, 0, stream>>>(tmp, bs, rowptr, dinv, dsq, col, N, E);

    gemm_k<<<(N + 127) / 128, 320, 0, stream>>>(x, W, dinv, Z0bf, N);

    int pgrid = (N + NPB - 1) / NPB;
    prop_k<false><<<pgrid, 256, 0, stream>>>(rowptr, col, dinv, dsq, b,
                                             Z0bf, Zb, nullptr, N);
    prop_k<true><<<pgrid, 256, 0, stream>>>(rowptr, col, dinv, dsq, b,
                                            Zb, nullptr, (float*)d_out, N);
}

// Round 7
// 1847.911 us; speedup vs baseline: 1.0232x; 1.0232x over previous
//
#include <hip/hip_runtime.h>
#include <math.h>

// SGC: out = log_softmax((A_hat^2 x) W + b), A_hat = D^-1/2 (A+I) D^-1/2
// (A^2 X) W == A^2 (X W): propagate in 40-dim class space.
// Z = D^-1/2 Y: Z' = di^2 (sum_s Z_s + Z_i) -> pure gather-add.
// Gathered Z buffers bf16 (80 B rows = 2 lines/edge, 8 MB footprint).
// Round-7: gemm inner loop uses EXPLICIT float4 accumulators/components.
// Round-6's wv[8]/acc[2][8] locals got demoted to scratch (3.2 GB HBM spill
// traffic, 1691 us). No indexable locals in hot loops.

#define FDIM 128
#define CDIM 40
#define C4   10
#define BKT_SHIFT 8
#define NB   512   // bucket slots (>= ceil(N/256))
#define NBLK 512   // edge-partition blocks
#define NPB  51    // nodes per 256-thread prop block (5 lanes/node)

// ---------- bf16 helpers (RTNE pack; finite inputs) ----------
__device__ __forceinline__ unsigned int bf16rn(float f) {
    unsigned int u = __float_as_uint(f);
    return (u + 0x7fffu + ((u >> 16) & 1u)) >> 16;
}
__device__ __forceinline__ unsigned int pack2(float lo, float hi) {
    unsigned int a = bf16rn(lo);
    unsigned int b = __float_as_uint(hi);
    b = (b + 0x7fffu + ((b >> 16) & 1u)) & 0xffff0000u;
    return a | b;
}
__device__ __forceinline__ void addu4(uint4 u, float* a) {
    a[0] += __uint_as_float(u.x << 16);
    a[1] += __uint_as_float(u.x & 0xffff0000u);
    a[2] += __uint_as_float(u.y << 16);
    a[3] += __uint_as_float(u.y & 0xffff0000u);
    a[4] += __uint_as_float(u.z << 16);
    a[5] += __uint_as_float(u.z & 0xffff0000u);
    a[6] += __uint_as_float(u.w << 16);
    a[7] += __uint_as_float(u.w & 0xffff0000u);
}

// ---- pass 1: per-block histogram over dst buckets (LDS, no global atomics)
__global__ void hist_k(const int* __restrict__ dst, int* __restrict__ G,
                       int E, int EB) {
    __shared__ int h[NB];
    int t = threadIdx.x;
    for (int i = t; i < NB; i += 256) h[i] = 0;
    __syncthreads();
    int s = blockIdx.x * EB;
    int e = min(s + EB, E);
    for (int i = s + t; i < e; i += 256)
        atomicAdd(&h[dst[i] >> BKT_SHIFT], 1);
    __syncthreads();
    for (int i = t; i < NB; i += 256) G[blockIdx.x * NB + i] = h[i];
}

// ---- pass 2: per-bucket exclusive scan over blocks (in-place on G); totals->T
__global__ void colscan_k(int* __restrict__ G, int* __restrict__ T) {
    __shared__ int lds[256];
    int j = blockIdx.x;
    int t = threadIdx.x;
    int v0 = G[(2 * t) * NB + j];
    int v1 = G[(2 * t + 1) * NB + j];
    int s = v0 + v1;
    lds[t] = s;
    __syncthreads();
    for (int off = 1; off < 256; off <<= 1) {
        int a = (t >= off) ? lds[t - off] : 0;
        __syncthreads();
        lds[t] += a;
        __syncthreads();
    }
    int excl = lds[t] - s;
    G[(2 * t) * NB + j] = excl;
    G[(2 * t + 1) * NB + j] = excl + v0;
    if (t == 255) T[j] = lds[255];
}

// ---- pass 2b: exclusive scan of bucket totals -> bs[0..NB], bs[NB]=E
__global__ void bscan_k(const int* __restrict__ T, int* __restrict__ bs) {
    __shared__ int lds[256];
    int t = threadIdx.x;
    int v0 = T[2 * t];
    int v1 = T[2 * t + 1];
    int s = v0 + v1;
    lds[t] = s;
    __syncthreads();
    for (int off = 1; off < 256; off <<= 1) {
        int a = (t >= off) ? lds[t - off] : 0;
        __syncthreads();
        lds[t] += a;
        __syncthreads();
    }
    int excl = lds[t] - s;
    bs[2 * t] = excl;
    bs[2 * t + 1] = excl + v0;
    if (t == 255) bs[NB] = lds[255];
}

// ---- pass 3: scatter packed edges into bucket-partitioned tmp
// pack: src (24 bits) | dstLocal (8 bits) << 24   [requires N < 2^24]
__global__ void part_k(const int* __restrict__ src, const int* __restrict__ dst,
                       const int* __restrict__ G, const int* __restrict__ bs,
                       unsigned int* __restrict__ tmp, int E, int EB) {
    __shared__ int offs[NB];
    __shared__ int cur[NB];
    int t = threadIdx.x;
    for (int i = t; i < NB; i += 256) {
        offs[i] = bs[i] + G[blockIdx.x * NB + i];
        cur[i] = 0;
    }
    __syncthreads();
    int s = blockIdx.x * EB;
    int e = min(s + EB, E);
    for (int i = s + t; i < e; i += 256) {
        int d = dst[i];
        int j = d >> BKT_SHIFT;
        int r = atomicAdd(&cur[j], 1);
        tmp[offs[j] + r] = (unsigned int)src[i] | ((unsigned int)(d & 255) << 24);
    }
}

// ---- pass 4: one block per bucket: rowptr/dinv/dsq + CSR col fill (all local)
__global__ void csr_k(const unsigned int* __restrict__ tmp, const int* __restrict__ bs,
                      int* __restrict__ rowptr, float* __restrict__ dinv,
                      float* __restrict__ dsq, int* __restrict__ col, int N, int E) {
    __shared__ int cnt[256];
    __shared__ int ptr[256];
    int j = blockIdx.x;
    int t = threadIdx.x;
    int base = j << BKT_SHIFT;
    int s = bs[j];
    int e = bs[j + 1];
    cnt[t] = 0;
    __syncthreads();
    for (int i = s + t; i < e; i += 256)
        atomicAdd(&cnt[tmp[i] >> 24], 1);
    __syncthreads();
    int v = cnt[t];
    ptr[t] = v;
    __syncthreads();
    for (int off = 1; off < 256; off <<= 1) {
        int a = (t >= off) ? ptr[t - off] : 0;
        __syncthreads();
        ptr[t] += a;
        __syncthreads();
    }
    int excl = ptr[t] - v;
    int node = base + t;
    if (node < N) {
        rowptr[node] = s + excl;
        float d = (float)(v + 1);              // +1 self-loop
        dinv[node] = rsqrtf(d);
        dsq[node] = sqrtf(d);
    }
    if (j == 0 && t == 0) rowptr[N] = E;
    cnt[t] = excl;  // cursor
    __syncthreads();
    for (int i = s + t; i < e; i += 256) {
        unsigned int p = tmp[i];
        int loc = p >> 24;
        int r = atomicAdd(&cnt[loc], 1);
        col[s + r] = (int)(p & 0xFFFFFF);
    }
}

// ---- Z0[node][40] (bf16) = dinv[node] * (x[node] @ W)
// 128-node tile, 320 threads; thread = 2 nodes x 8 classes.
// Explicit float4 accumulators (a0l/a0h/a1l/a1h) -- NO indexable locals.
__global__ __launch_bounds__(320) void gemm_k(const float* __restrict__ x,
                                              const float* __restrict__ W,
                                              const float* __restrict__ dinv,
                                              uint4* __restrict__ Zbf, int n) {
    __shared__ float Ws[FDIM * CDIM];   // 20 KB
    __shared__ float xT[32][129];       // 16.5 KB
    int t = threadIdx.x;
    for (int i = t; i < FDIM * CDIM; i += 320) Ws[i] = W[i];
    int base = blockIdx.x * 128;
    int cg = t >> 6;   // 0..4 (8 classes each) -> one uint4 per node
    int ng = t & 63;   // nodes {ng, ng+64}
    float4 a0l = make_float4(0.f, 0.f, 0.f, 0.f);
    float4 a0h = make_float4(0.f, 0.f, 0.f, 0.f);
    float4 a1l = make_float4(0.f, 0.f, 0.f, 0.f);
    float4 a1h = make_float4(0.f, 0.f, 0.f, 0.f);

    for (int ch = 0; ch < 4; ++ch) {
        __syncthreads();
        for (int i = t; i < 1024; i += 320) {
            int f4 = i & 7;
            int nn = i >> 3;
            int node = base + nn;
            float4 xv = make_float4(0.f, 0.f, 0.f, 0.f);
            if (node < n)
                xv = *(const float4*)(x + (size_t)node * FDIM + ch * 32 + f4 * 4);
            xT[f4 * 4 + 0][nn] = xv.x;
            xT[f4 * 4 + 1][nn] = xv.y;
            xT[f4 * 4 + 2][nn] = xv.z;
            xT[f4 * 4 + 3][nn] = xv.w;
        }
        __syncthreads();
        for (int f = 0; f < 32; ++f) {
            float x0 = xT[f][ng];
            float x1 = xT[f][ng + 64];
            const float* wr = &Ws[(ch * 32 + f) * CDIM + cg * 8];
            float4 w0 = *(const float4*)(wr);
            float4 w1 = *(const float4*)(wr + 4);
            a0l.x += x0 * w0.x; a0l.y += x0 * w0.y;
            a0l.z += x0 * w0.z; a0l.w += x0 * w0.w;
            a0h.x += x0 * w1.x; a0h.y += x0 * w1.y;
            a0h.z += x0 * w1.z; a0h.w += x0 * w1.w;
            a1l.x += x1 * w0.x; a1l.y += x1 * w0.y;
            a1l.z += x1 * w0.z; a1l.w += x1 * w0.w;
            a1h.x += x1 * w1.x; a1h.y += x1 * w1.y;
            a1h.z += x1 * w1.z; a1h.w += x1 * w1.w;
        }
    }
    int node0 = base + ng;
    if (node0 < n) {
        float di = dinv[node0];
        uint4 o;
        o.x = pack2(a0l.x * di, a0l.y * di);
        o.y = pack2(a0l.z * di, a0l.w * di);
        o.z = pack2(a0h.x * di, a0h.y * di);
        o.w = pack2(a0h.z * di, a0h.w * di);
        Zbf[(size_t)node0 * 5 + cg] = o;
    }
    int node1 = base + ng + 64;
    if (node1 < n) {
        float di = dinv[node1];
        uint4 o;
        o.x = pack2(a1l.x * di, a1l.y * di);
        o.y = pack2(a1l.z * di, a1l.w * di);
        o.z = pack2(a1h.x * di, a1h.y * di);
        o.w = pack2(a1h.z * di, a1h.w * di);
        Zbf[(size_t)node1 * 5 + cg] = o;
    }
}

// ---- one hop: acc = sum_{s->i} Zin[s] + Zin[i]; Zout = di^2 * acc.
// FINAL: fuse logits = Z2*dsq + b and log_softmax, write fp32 d_out.
// 5 lanes/node x uint4 (8 bf16); 51 nodes per 256-thread block.
template <bool FINAL>
__global__ __launch_bounds__(256) void prop_k(const int* __restrict__ rowptr,
                                              const int* __restrict__ col,
                                              const float* __restrict__ dinv,
                                              const float* __restrict__ dsq,
                                              const float* __restrict__ bias,
                                              const uint4* __restrict__ Zin,
                                              uint4* __restrict__ Zout_bf,
                                              float* __restrict__ out_f32, int n) {
    __shared__ float bsm[CDIM];
    __shared__ float red[256];
    int t = threadIdx.x;
    if (FINAL && t < CDIM) bsm[t] = bias[t];
    int g = t / 5;
    int c8 = t - g * 5;
    int node = blockIdx.x * NPB + g;
    bool active = (g < NPB) && (node < n);
    float acc[8];
    #pragma unroll
    for (int c = 0; c < 8; ++c) acc[c] = 0.f;
    float w = 0.f;
    if (active) {
        float di = dinv[node];
        w = di * di;
        addu4(Zin[(size_t)node * 5 + c8], acc);   // self-loop
        int e = rowptr[node];
        int end = rowptr[node + 1];
        for (; e + 3 < end; e += 4) {
            int s0 = col[e], s1 = col[e + 1], s2 = col[e + 2], s3 = col[e + 3];
            uint4 a0 = Zin[(size_t)s0 * 5 + c8];
            uint4 a1 = Zin[(size_t)s1 * 5 + c8];
            uint4 a2 = Zin[(size_t)s2 * 5 + c8];
            uint4 a3 = Zin[(size_t)s3 * 5 + c8];
            addu4(a0, acc); addu4(a1, acc); addu4(a2, acc); addu4(a3, acc);
        }
        for (; e < end; ++e)
            addu4(Zin[(size_t)col[e] * 5 + c8], acc);
    }

    if (!FINAL) {
        if (active) {
            uint4 o;
            o.x = pack2(acc[0] * w, acc[1] * w);
            o.y = pack2(acc[2] * w, acc[3] * w);
            o.z = pack2(acc[4] * w, acc[5] * w);
            o.w = pack2(acc[6] * w, acc[7] * w);
            Zout_bf[(size_t)node * 5 + c8] = o;
        }
        return;
    }

    // FINAL: logits + log_softmax via 5-lane LDS reduction.
    __syncthreads();  // bsm ready
    float v[8];
    float m8 = -INFINITY;
    if (active) {
        float ws_ = w * dsq[node];
        #pragma unroll
        for (int j = 0; j < 8; ++j) {
            v[j] = acc[j] * ws_ + bsm[c8 * 8 + j];
            m8 = fmaxf(m8, v[j]);
        }
    }
    red[t] = m8;
    __syncthreads();
    float m = m8;
    if (active) {
        int rb = g * 5;
        m = fmaxf(fmaxf(fmaxf(red[rb], red[rb + 1]), fmaxf(red[rb + 2], red[rb + 3])),
                  red[rb + 4]);
    }
    float s8 = 0.f;
    if (active) {
        #pragma unroll
        for (int j = 0; j < 8; ++j) s8 += expf(v[j] - m);
    }
    __syncthreads();
    red[t] = s8;
    __syncthreads();
    if (active) {
        int rb = g * 5;
        float s = (red[rb] + red[rb + 1]) + (red[rb + 2] + red[rb + 3]) + red[rb + 4];
        float ls = m + logf(s);
        float* p = out_f32 + (size_t)node * CDIM + c8 * 8;
        *(float4*)p = make_float4(v[0] - ls, v[1] - ls, v[2] - ls, v[3] - ls);
        *(float4*)(p + 4) = make_float4(v[4] - ls, v[5] - ls, v[6] - ls, v[7] - ls);
    }
}

extern "C" void kernel_launch(void* const* d_in, const int* in_sizes, int n_in,
                              void* d_out, int out_size, void* d_ws, size_t ws_size,
                              hipStream_t stream) {
    const float* x = (const float*)d_in[0];
    const float* W = (const float*)d_in[1];
    const float* b = (const float*)d_in[2];
    const int* ei = (const int*)d_in[3];

    int C = in_sizes[2];            // 40
    int F = in_sizes[1] / C;        // 128
    int N = in_sizes[0] / F;        // 100000
    int E = in_sizes[3] / 2;        // 1600000
    const int* src = ei;
    const int* dst = ei + E;

    // workspace: union region holds {G,T,bs,tmp} during build, then Z0bf (8MB).
    // Zb (hop-1 bf16 out, 8MB) separate: hop-2 gathers from it while writing
    // d_out, so it must not alias d_out.
    char* ws = (char*)d_ws;
    size_t goff = 0;
    int* G = (int*)(ws + goff);                       goff += (size_t)NBLK * NB * 4;
    int* T = (int*)(ws + goff);                       goff += (size_t)NB * 4;
    int* bs = (int*)(ws + goff);                      goff += (size_t)(NB + 1) * 4 + 12;
    goff = (goff + 15) & ~(size_t)15;
    unsigned int* tmp = (unsigned int*)(ws + goff);   goff += (size_t)E * 4;
    size_t z0bytes = (size_t)N * 80;                  // 5 x uint4 per node
    size_t unionEnd = (z0bytes > goff) ? z0bytes : goff;
    unionEnd = (unionEnd + 15) & ~(size_t)15;
    uint4* Z0bf = (uint4*)ws;        // overlays build scratch
    size_t off = unionEnd;
    int* rowptr = (int*)(ws + off); off += ((size_t)(N + 1) * 4 + 15) & ~(size_t)15;
    float* dinv = (float*)(ws + off); off += ((size_t)N * 4 + 15) & ~(size_t)15;
    float* dsq = (float*)(ws + off); off += ((size_t)N * 4 + 15) & ~(size_t)15;
    int* col = (int*)(ws + off); off += ((size_t)E * 4 + 15) & ~(size_t)15;
    uint4* Zb = (uint4*)(ws + off); off += (z0bytes + 15) & ~(size_t)15;

    int EB = (E + NBLK - 1) / NBLK;
    int NBr = (N + 255) >> BKT_SHIFT;

    hist_k<<<NBLK, 256, 0, stream>>>(dst, G, E, EB);
    colscan_k<<<NB, 256, 0, stream>>>(G, T);
    bscan_k<<<1, 256, 0, stream>>>(T, bs);
    part_k<<<NBLK, 256, 0, stream>>>(src, dst, G, bs, tmp, E, EB);
    csr_k<<<NBr, 256, 0, stream>>>(tmp, bs, rowptr, dinv, dsq, col, N, E);

    gemm_k<<<(N + 127) / 128, 320, 0, stream>>>(x, W, dinv, Z0bf, N);

    int pgrid = (N + NPB - 1) / NPB;
    prop_k<false><<<pgrid, 256, 0, stream>>>(rowptr, col, dinv, dsq, b,
                                             Z0bf, Zb, nullptr, N);
    prop_k<true><<<pgrid, 256, 0, stream>>>(rowptr, col, dinv, dsq, b,
                                            Zb, nullptr, (float*)d_out, N);
}

// Round 8
// 238.964 us; speedup vs baseline: 7.9121x; 7.7330x over previous
//
#include <hip/hip_runtime.h>
#include <math.h>

// SGC: out = log_softmax((A_hat^2 x) W + b), A_hat = D^-1/2 (A+I) D^-1/2
// (A^2 X) W == A^2 (X W): propagate in 40-dim class space.
// Z = D^-1/2 Y: Z' = di^2 (sum_s Z_s + Z_i) -> pure gather-add.
// Gathered Z buffers bf16 (80 B rows = 2 lines/edge, 8 MB footprint).
// Round-8: gemm_k reverted VERBATIM to round-5's known-good version
// (256-node tile, VGPR 52, 46.5 us). Both 128-node retiles (rounds 6,7)
// produced VGPR-128 + ~3.4 GB scratch spill traffic regardless of whether
// the inner loop used wv[8] or explicit float4 scalars -- tile-dependent
// codegen pathology, needs disasm to root-cause. Keep the hop-2 fusion
// (bias + log_softmax in prop_k<true>), which kills final_k's 32 MB
// round-trip + one launch.

#define FDIM 128
#define CDIM 40
#define C4   10
#define BKT_SHIFT 8
#define NB   512   // bucket slots (>= ceil(N/256))
#define NBLK 512   // edge-partition blocks
#define NPB  51    // nodes per 256-thread prop block (5 lanes/node)

// ---------- bf16 helpers (RTNE pack; finite inputs) ----------
__device__ __forceinline__ unsigned int bf16rn(float f) {
    unsigned int u = __float_as_uint(f);
    return (u + 0x7fffu + ((u >> 16) & 1u)) >> 16;
}
__device__ __forceinline__ unsigned int pack2(float lo, float hi) {
    unsigned int a = bf16rn(lo);
    unsigned int b = __float_as_uint(hi);
    b = (b + 0x7fffu + ((b >> 16) & 1u)) & 0xffff0000u;
    return a | b;
}
__device__ __forceinline__ void addu4(uint4 u, float* a) {
    a[0] += __uint_as_float(u.x << 16);
    a[1] += __uint_as_float(u.x & 0xffff0000u);
    a[2] += __uint_as_float(u.y << 16);
    a[3] += __uint_as_float(u.y & 0xffff0000u);
    a[4] += __uint_as_float(u.z << 16);
    a[5] += __uint_as_float(u.z & 0xffff0000u);
    a[6] += __uint_as_float(u.w << 16);
    a[7] += __uint_as_float(u.w & 0xffff0000u);
}

// ---- pass 1: per-block histogram over dst buckets (LDS, no global atomics)
__global__ void hist_k(const int* __restrict__ dst, int* __restrict__ G,
                       int E, int EB) {
    __shared__ int h[NB];
    int t = threadIdx.x;
    for (int i = t; i < NB; i += 256) h[i] = 0;
    __syncthreads();
    int s = blockIdx.x * EB;
    int e = min(s + EB, E);
    for (int i = s + t; i < e; i += 256)
        atomicAdd(&h[dst[i] >> BKT_SHIFT], 1);
    __syncthreads();
    for (int i = t; i < NB; i += 256) G[blockIdx.x * NB + i] = h[i];
}

// ---- pass 2: per-bucket exclusive scan over blocks (in-place on G); totals->T
__global__ void colscan_k(int* __restrict__ G, int* __restrict__ T) {
    __shared__ int lds[256];
    int j = blockIdx.x;
    int t = threadIdx.x;
    int v0 = G[(2 * t) * NB + j];
    int v1 = G[(2 * t + 1) * NB + j];
    int s = v0 + v1;
    lds[t] = s;
    __syncthreads();
    for (int off = 1; off < 256; off <<= 1) {
        int a = (t >= off) ? lds[t - off] : 0;
        __syncthreads();
        lds[t] += a;
        __syncthreads();
    }
    int excl = lds[t] - s;
    G[(2 * t) * NB + j] = excl;
    G[(2 * t + 1) * NB + j] = excl + v0;
    if (t == 255) T[j] = lds[255];
}

// ---- pass 2b: exclusive scan of bucket totals -> bs[0..NB], bs[NB]=E
__global__ void bscan_k(const int* __restrict__ T, int* __restrict__ bs) {
    __shared__ int lds[256];
    int t = threadIdx.x;
    int v0 = T[2 * t];
    int v1 = T[2 * t + 1];
    int s = v0 + v1;
    lds[t] = s;
    __syncthreads();
    for (int off = 1; off < 256; off <<= 1) {
        int a = (t >= off) ? lds[t - off] : 0;
        __syncthreads();
        lds[t] += a;
        __syncthreads();
    }
    int excl = lds[t] - s;
    bs[2 * t] = excl;
    bs[2 * t + 1] = excl + v0;
    if (t == 255) bs[NB] = lds[255];
}

// ---- pass 3: scatter packed edges into bucket-partitioned tmp
// pack: src (24 bits) | dstLocal (8 bits) << 24   [requires N < 2^24]
__global__ void part_k(const int* __restrict__ src, const int* __restrict__ dst,
                       const int* __restrict__ G, const int* __restrict__ bs,
                       unsigned int* __restrict__ tmp, int E, int EB) {
    __shared__ int offs[NB];
    __shared__ int cur[NB];
    int t = threadIdx.x;
    for (int i = t; i < NB; i += 256) {
        offs[i] = bs[i] + G[blockIdx.x * NB + i];
        cur[i] = 0;
    }
    __syncthreads();
    int s = blockIdx.x * EB;
    int e = min(s + EB, E);
    for (int i = s + t; i < e; i += 256) {
        int d = dst[i];
        int j = d >> BKT_SHIFT;
        int r = atomicAdd(&cur[j], 1);
        tmp[offs[j] + r] = (unsigned int)src[i] | ((unsigned int)(d & 255) << 24);
    }
}

// ---- pass 4: one block per bucket: rowptr/dinv/dsq + CSR col fill (all local)
__global__ void csr_k(const unsigned int* __restrict__ tmp, const int* __restrict__ bs,
                      int* __restrict__ rowptr, float* __restrict__ dinv,
                      float* __restrict__ dsq, int* __restrict__ col, int N, int E) {
    __shared__ int cnt[256];
    __shared__ int ptr[256];
    int j = blockIdx.x;
    int t = threadIdx.x;
    int base = j << BKT_SHIFT;
    int s = bs[j];
    int e = bs[j + 1];
    cnt[t] = 0;
    __syncthreads();
    for (int i = s + t; i < e; i += 256)
        atomicAdd(&cnt[tmp[i] >> 24], 1);
    __syncthreads();
    int v = cnt[t];
    ptr[t] = v;
    __syncthreads();
    for (int off = 1; off < 256; off <<= 1) {
        int a = (t >= off) ? ptr[t - off] : 0;
        __syncthreads();
        ptr[t] += a;
        __syncthreads();
    }
    int excl = ptr[t] - v;
    int node = base + t;
    if (node < N) {
        rowptr[node] = s + excl;
        float d = (float)(v + 1);              // +1 self-loop
        dinv[node] = rsqrtf(d);
        dsq[node] = sqrtf(d);
    }
    if (j == 0 && t == 0) rowptr[N] = E;
    cnt[t] = excl;  // cursor
    __syncthreads();
    for (int i = s + t; i < e; i += 256) {
        unsigned int p = tmp[i];
        int loc = p >> 24;
        int r = atomicAdd(&cnt[loc], 1);
        col[s + r] = (int)(p & 0xFFFFFF);
    }
}

// ---- Z0[node][40] (bf16) = dinv[node] * (x[node] @ W)
// ROUND-5 KNOWN-GOOD VERSION (VGPR 52, no scratch): 256-node tile,
// 320 threads; thread tile = 4 nodes x 8 classes.
__global__ __launch_bounds__(320) void gemm_k(const float* __restrict__ x,
                                              const float* __restrict__ W,
                                              const float* __restrict__ dinv,
                                              uint4* __restrict__ Zbf, int n) {
    __shared__ float Ws[FDIM * CDIM];   // 20 KB
    __shared__ float xT[32][257];       // 32.9 KB
    int t = threadIdx.x;
    for (int i = t; i < FDIM * CDIM; i += 320) Ws[i] = W[i];
    int base = blockIdx.x * 256;
    int cg = t >> 6;   // 0..4 (8 classes each) -> one uint4 per node
    int ng = t & 63;
    float acc[4][8];
    #pragma unroll
    for (int k = 0; k < 4; ++k)
        #pragma unroll
        for (int c = 0; c < 8; ++c) acc[k][c] = 0.f;

    for (int ch = 0; ch < 4; ++ch) {
        __syncthreads();
        for (int i = t; i < 2048; i += 320) {
            int f4 = i & 7;
            int nn = i >> 3;
            int node = base + nn;
            float4 xv = make_float4(0.f, 0.f, 0.f, 0.f);
            if (node < n)
                xv = *(const float4*)(x + (size_t)node * FDIM + ch * 32 + f4 * 4);
            xT[f4 * 4 + 0][nn] = xv.x;
            xT[f4 * 4 + 1][nn] = xv.y;
            xT[f4 * 4 + 2][nn] = xv.z;
            xT[f4 * 4 + 3][nn] = xv.w;
        }
        __syncthreads();
        for (int f = 0; f < 32; ++f) {
            float x0 = xT[f][ng];
            float x1 = xT[f][ng + 64];
            float x2 = xT[f][ng + 128];
            float x3 = xT[f][ng + 192];
            const float* wr = &Ws[(ch * 32 + f) * CDIM + cg * 8];
            float4 w0 = *(const float4*)(wr);
            float4 w1 = *(const float4*)(wr + 4);
            float wv[8] = {w0.x, w0.y, w0.z, w0.w, w1.x, w1.y, w1.z, w1.w};
            #pragma unroll
            for (int c = 0; c < 8; ++c) {
                acc[0][c] += x0 * wv[c];
                acc[1][c] += x1 * wv[c];
                acc[2][c] += x2 * wv[c];
                acc[3][c] += x3 * wv[c];
            }
        }
    }
    #pragma unroll
    for (int k = 0; k < 4; ++k) {
        int node = base + ng + 64 * k;
        if (node >= n) continue;
        float di = dinv[node];
        uint4 o;
        o.x = pack2(acc[k][0] * di, acc[k][1] * di);
        o.y = pack2(acc[k][2] * di, acc[k][3] * di);
        o.z = pack2(acc[k][4] * di, acc[k][5] * di);
        o.w = pack2(acc[k][6] * di, acc[k][7] * di);
        Zbf[(size_t)node * 5 + cg] = o;
    }
}

// ---- one hop: acc = sum_{s->i} Zin[s] + Zin[i]; Zout = di^2 * acc.
// FINAL: fuse logits = Z2*dsq + b and log_softmax, write fp32 d_out.
// 5 lanes/node x uint4 (8 bf16); 51 nodes per 256-thread block.
template <bool FINAL>
__global__ __launch_bounds__(256) void prop_k(const int* __restrict__ rowptr,
                                              const int* __restrict__ col,
                                              const float* __restrict__ dinv,
                                              const float* __restrict__ dsq,
                                              const float* __restrict__ bias,
                                              const uint4* __restrict__ Zin,
                                              uint4* __restrict__ Zout_bf,
                                              float* __restrict__ out_f32, int n) {
    __shared__ float bsm[CDIM];
    __shared__ float red[256];
    int t = threadIdx.x;
    if (FINAL && t < CDIM) bsm[t] = bias[t];
    int g = t / 5;
    int c8 = t - g * 5;
    int node = blockIdx.x * NPB + g;
    bool active = (g < NPB) && (node < n);
    float acc[8];
    #pragma unroll
    for (int c = 0; c < 8; ++c) acc[c] = 0.f;
    float w = 0.f;
    if (active) {
        float di = dinv[node];
        w = di * di;
        addu4(Zin[(size_t)node * 5 + c8], acc);   // self-loop
        int e = rowptr[node];
        int end = rowptr[node + 1];
        for (; e + 3 < end; e += 4) {
            int s0 = col[e], s1 = col[e + 1], s2 = col[e + 2], s3 = col[e + 3];
            uint4 a0 = Zin[(size_t)s0 * 5 + c8];
            uint4 a1 = Zin[(size_t)s1 * 5 + c8];
            uint4 a2 = Zin[(size_t)s2 * 5 + c8];
            uint4 a3 = Zin[(size_t)s3 * 5 + c8];
            addu4(a0, acc); addu4(a1, acc); addu4(a2, acc); addu4(a3, acc);
        }
        for (; e < end; ++e)
            addu4(Zin[(size_t)col[e] * 5 + c8], acc);
    }

    if (!FINAL) {
        if (active) {
            uint4 o;
            o.x = pack2(acc[0] * w, acc[1] * w);
            o.y = pack2(acc[2] * w, acc[3] * w);
            o.z = pack2(acc[4] * w, acc[5] * w);
            o.w = pack2(acc[6] * w, acc[7] * w);
            Zout_bf[(size_t)node * 5 + c8] = o;
        }
        return;
    }

    // FINAL: logits + log_softmax via 5-lane LDS reduction.
    __syncthreads();  // bsm ready
    float v[8];
    float m8 = -INFINITY;
    if (active) {
        float ws_ = w * dsq[node];
        #pragma unroll
        for (int j = 0; j < 8; ++j) {
            v[j] = acc[j] * ws_ + bsm[c8 * 8 + j];
            m8 = fmaxf(m8, v[j]);
        }
    }
    red[t] = m8;
    __syncthreads();
    float m = m8;
    if (active) {
        int rb = g * 5;
        m = fmaxf(fmaxf(fmaxf(red[rb], red[rb + 1]), fmaxf(red[rb + 2], red[rb + 3])),
                  red[rb + 4]);
    }
    float s8 = 0.f;
    if (active) {
        #pragma unroll
        for (int j = 0; j < 8; ++j) s8 += expf(v[j] - m);
    }
    __syncthreads();
    red[t] = s8;
    __syncthreads();
    if (active) {
        int rb = g * 5;
        float s = (red[rb] + red[rb + 1]) + (red[rb + 2] + red[rb + 3]) + red[rb + 4];
        float ls = m + logf(s);
        float* p = out_f32 + (size_t)node * CDIM + c8 * 8;
        *(float4*)p = make_float4(v[0] - ls, v[1] - ls, v[2] - ls, v[3] - ls);
        *(float4*)(p + 4) = make_float4(v[4] - ls, v[5] - ls, v[6] - ls, v[7] - ls);
    }
}

extern "C" void kernel_launch(void* const* d_in, const int* in_sizes, int n_in,
                              void* d_out, int out_size, void* d_ws, size_t ws_size,
                              hipStream_t stream) {
    const float* x = (const float*)d_in[0];
    const float* W = (const float*)d_in[1];
    const float* b = (const float*)d_in[2];
    const int* ei = (const int*)d_in[3];

    int C = in_sizes[2];            // 40
    int F = in_sizes[1] / C;        // 128
    int N = in_sizes[0] / F;        // 100000
    int E = in_sizes[3] / 2;        // 1600000
    const int* src = ei;
    const int* dst = ei + E;

    // workspace: union region holds {G,T,bs,tmp} during build, then Z0bf (8MB).
    // Zb (hop-1 bf16 out, 8MB) separate: hop-2 gathers from it while writing
    // d_out, so it must not alias d_out.
    char* ws = (char*)d_ws;
    size_t goff = 0;
    int* G = (int*)(ws + goff);                       goff += (size_t)NBLK * NB * 4;
    int* T = (int*)(ws + goff);                       goff += (size_t)NB * 4;
    int* bs = (int*)(ws + goff);                      goff += (size_t)(NB + 1) * 4 + 12;
    goff = (goff + 15) & ~(size_t)15;
    unsigned int* tmp = (unsigned int*)(ws + goff);   goff += (size_t)E * 4;
    size_t z0bytes = (size_t)N * 80;                  // 5 x uint4 per node
    size_t unionEnd = (z0bytes > goff) ? z0bytes : goff;
    unionEnd = (unionEnd + 15) & ~(size_t)15;
    uint4* Z0bf = (uint4*)ws;        // overlays build scratch
    size_t off = unionEnd;
    int* rowptr = (int*)(ws + off); off += ((size_t)(N + 1) * 4 + 15) & ~(size_t)15;
    float* dinv = (float*)(ws + off); off += ((size_t)N * 4 + 15) & ~(size_t)15;
    float* dsq = (float*)(ws + off); off += ((size_t)N * 4 + 15) & ~(size_t)15;
    int* col = (int*)(ws + off); off += ((size_t)E * 4 + 15) & ~(size_t)15;
    uint4* Zb = (uint4*)(ws + off); off += (z0bytes + 15) & ~(size_t)15;

    int EB = (E + NBLK - 1) / NBLK;
    int NBr = (N + 255) >> BKT_SHIFT;

    hist_k<<<NBLK, 256, 0, stream>>>(dst, G, E, EB);
    colscan_k<<<NB, 256, 0, stream>>>(G, T);
    bscan_k<<<1, 256, 0, stream>>>(T, bs);
    part_k<<<NBLK, 256, 0, stream>>>(src, dst, G, bs, tmp, E, EB);
    csr_k<<<NBr, 256, 0, stream>>>(tmp, bs, rowptr, dinv, dsq, col, N, E);

    gemm_k<<<(N + 255) / 256, 320, 0, stream>>>(x, W, dinv, Z0bf, N);

    int pgrid = (N + NPB - 1) / NPB;
    prop_k<false><<<pgrid, 256, 0, stream>>>(rowptr, col, dinv, dsq, b,
                                             Z0bf, Zb, nullptr, N);
    prop_k<true><<<pgrid, 256, 0, stream>>>(rowptr, col, dinv, dsq, b,
                                            Zb, nullptr, (float*)d_out, N);
}